// Round 1
// baseline (453.828 us; speedup 1.0000x reference)
//
#include <hip/hip_runtime.h>

// LUT piecewise-linear: out = a[idx]*d + b[idx], idx = #{x_i < d}, K=1024 sorted x.
// v1: LDS-resident tables, branchless 11-probe binary search, swizzled x layout
// to break the bank-31 pileup at search levels s<=128, float4 global I/O.

#define LUT_K 1024
#define XPAD (LUT_K + (LUT_K / 32))  // 1056 floats: addr(i) = i + i/32

__device__ __forceinline__ int swiz(int i) { return i + (i >> 5); }

__global__ __launch_bounds__(256) void lut_kernel(
    const float* __restrict__ data, const float* __restrict__ x,
    const float* __restrict__ a, const float* __restrict__ b,
    float* __restrict__ out, int n4)
{
    __shared__ float xs[XPAD];
    __shared__ float2 ab[LUT_K + 1];

    for (int i = threadIdx.x; i < LUT_K; i += blockDim.x)
        xs[swiz(i)] = x[i];
    for (int i = threadIdx.x; i < LUT_K + 1; i += blockDim.x)
        ab[i] = make_float2(a[i], b[i]);
    __syncthreads();

    const float4* __restrict__ in4 = (const float4*)data;
    float4* __restrict__ out4 = (float4*)out;

    auto eval = [&](float v) -> float {
        // pos = count of x_i < v  (== searchsorted(x, v, side='left'))
        int pos = 0;
        #pragma unroll
        for (int s = 512; s > 0; s >>= 1)
            pos += (xs[swiz(pos + s - 1)] < v) ? s : 0;
        // pos in [0,1023]; one more compare extends range to [0,1024]
        pos += (xs[swiz(pos)] < v) ? 1 : 0;
        float2 c = ab[pos];
        return fmaf(c.x, v, c.y);
    };

    const int stride = gridDim.x * blockDim.x;
    for (int i = blockIdx.x * blockDim.x + threadIdx.x; i < n4; i += stride) {
        float4 d = in4[i];
        float4 r;
        r.x = eval(d.x);
        r.y = eval(d.y);
        r.z = eval(d.z);
        r.w = eval(d.w);
        out4[i] = r;
    }
}

extern "C" void kernel_launch(void* const* d_in, const int* in_sizes, int n_in,
                              void* d_out, int out_size, void* d_ws, size_t ws_size,
                              hipStream_t stream) {
    const float* data = (const float*)d_in[0];
    const float* x    = (const float*)d_in[1];
    const float* a    = (const float*)d_in[2];
    const float* b    = (const float*)d_in[3];
    float* out = (float*)d_out;

    int n  = in_sizes[0];      // 4096*16384 = 67108864, divisible by 4
    int n4 = n >> 2;

    dim3 block(256);
    dim3 grid(2048);           // 8 blocks/CU, grid-stride over 16.7M float4s
    lut_kernel<<<grid, block, 0, stream>>>(data, x, a, b, out, n4);
}

// Round 2
// 439.636 us; speedup vs baseline: 1.0323x; 1.0323x over previous
//
#include <hip/hip_runtime.h>

// LUT piecewise-linear: out = a[idx]*d + b[idx], idx = #{x_i < d}, K=1024 sorted x.
// v2: uniform-grid bucket table (M=8192) replaces 11-probe binary search.
//   idx = bs[bucket(v)] + short sorted scan  -> ~2 divergent LDS probes vs 11.
// Exactness: bucket() is the same monotone fp32 expression for breakpoints
// (setup kernel) and data (main kernel), so i < bs[j] => x_i < v, and the
// sorted scan completes the exact count. Sentinel xs[K]=+inf bounds the scan.

#define LUT_K 1024
#define NB    8192   // buckets
#define WS_NEEDED (NB * 2 + 8)  // uint16 bs[NB] + float params[2]

__device__ __forceinline__ int bucket_of(float v, float x0, float invw) {
    // trunc(mul(sub)) with forced IEEE ops: identical + monotone in both kernels
    int t = (int)__fmul_rn(__fsub_rn(v, x0), invw);
    t = t < 0 ? 0 : t;
    return t > (NB - 1) ? (NB - 1) : t;
}

// Build bs[j] = #{i : bucket_of(x_i) < j} and params into ws.
// ws layout: uint16 bs[NB] at 0; float {x0, invw} at NB*2.
__global__ __launch_bounds__(256) void build_kernel(const float* __restrict__ x, void* ws) {
    __shared__ float xs[LUT_K];
    unsigned short* bs = (unsigned short*)ws;
    float* params = (float*)((char*)ws + NB * 2);
    for (int i = threadIdx.x; i < LUT_K; i += blockDim.x) xs[i] = x[i];
    __syncthreads();
    const float x0 = xs[0];
    const float invw = (float)NB / (xs[LUT_K - 1] - x0);
    if (blockIdx.x == 0 && threadIdx.x == 0) { params[0] = x0; params[1] = invw; }
    int j = blockIdx.x * blockDim.x + threadIdx.x;
    if (j < NB) {
        // lower_bound: first i with bucket_of(x_i) >= j  (bucket_of monotone in x)
        int lo = 0, hi = LUT_K;
        while (lo < hi) {
            int mid = (lo + hi) >> 1;
            if (bucket_of(xs[mid], x0, invw) < j) lo = mid + 1; else hi = mid;
        }
        bs[j] = (unsigned short)lo;
    }
}

__global__ __launch_bounds__(256) void lut_main(
    const float* __restrict__ data, const float* __restrict__ x,
    const float* __restrict__ a, const float* __restrict__ b,
    const void* __restrict__ ws, float* __restrict__ out, int n4, int use_ws)
{
    __shared__ float xs[LUT_K + 1];
    __shared__ float aa[LUT_K + 1];
    __shared__ float bb[LUT_K + 1];
    __shared__ __align__(16) unsigned short bs[NB];

    for (int i = threadIdx.x; i < LUT_K; i += blockDim.x) xs[i] = x[i];
    for (int i = threadIdx.x; i < LUT_K + 1; i += blockDim.x) { aa[i] = a[i]; bb[i] = b[i]; }
    if (threadIdx.x == 0) xs[LUT_K] = __builtin_inff();

    float x0, invw;
    if (use_ws) {
        const float* params = (const float*)((const char*)ws + NB * 2);
        x0 = params[0]; invw = params[1];
        const uint2* gbs = (const uint2*)ws;               // stage 8B/thread
        for (int i = threadIdx.x; i < NB / 4; i += blockDim.x)
            ((uint2*)bs)[i] = gbs[i];
        __syncthreads();
    } else {
        // Fallback (tiny/absent workspace): build bs per-block from xs in LDS.
        __syncthreads();                                    // xs ready
        x0 = xs[0];
        invw = (float)NB / (xs[LUT_K - 1] - x0);
        for (int j = threadIdx.x; j < NB; j += blockDim.x) {
            int lo = 0, hi = LUT_K;
            while (lo < hi) {
                int mid = (lo + hi) >> 1;
                if (bucket_of(xs[mid], x0, invw) < j) lo = mid + 1; else hi = mid;
            }
            bs[j] = (unsigned short)lo;
        }
        __syncthreads();
    }

    const float4* __restrict__ in4 = (const float4*)data;
    float4* __restrict__ out4 = (float4*)out;

    auto eval = [&](float v) -> float {
        int j = bucket_of(v, x0, invw);
        int idx = bs[j];
        while (xs[idx] < v) idx++;   // avg ~0.3 extra probes; bounded by xs[K]=+inf
        return fmaf(aa[idx], v, bb[idx]);
    };

    const int stride = gridDim.x * blockDim.x;
    for (int i = blockIdx.x * blockDim.x + threadIdx.x; i < n4; i += stride) {
        float4 d = in4[i];
        float4 r;
        r.x = eval(d.x);
        r.y = eval(d.y);
        r.z = eval(d.z);
        r.w = eval(d.w);
        out4[i] = r;
    }
}

extern "C" void kernel_launch(void* const* d_in, const int* in_sizes, int n_in,
                              void* d_out, int out_size, void* d_ws, size_t ws_size,
                              hipStream_t stream) {
    const float* data = (const float*)d_in[0];
    const float* x    = (const float*)d_in[1];
    const float* a    = (const float*)d_in[2];
    const float* b    = (const float*)d_in[3];
    float* out = (float*)d_out;

    int n  = in_sizes[0];   // 4096*16384
    int n4 = n >> 2;

    int use_ws = (ws_size >= (size_t)WS_NEEDED) ? 1 : 0;
    if (use_ws)
        build_kernel<<<(NB + 255) / 256, 256, 0, stream>>>(x, d_ws);

    // LDS 28.7 KB/block -> 5 blocks/CU; grid = 5 * 256 CUs, grid-stride loop.
    lut_main<<<1280, 256, 0, stream>>>(data, x, a, b, d_ws, out, n4, use_ws);
}